// Round 15
// baseline (1922.788 us; speedup 1.0000x reference)
//
#include <hip/hip_runtime.h>
#include <hip/hip_bf16.h>

typedef __attribute__((ext_vector_type(4))) float f32x4;
typedef __attribute__((ext_vector_type(4))) int   i32x4;
typedef __attribute__((ext_vector_type(8))) short s16x8;
typedef unsigned short ushort_t;

#define MDIM 8192
#define KDIM 4096
#define NDIM 16384
#define NKT  64                 // 64 K-tiles of 64 int8 elems

static __device__ __forceinline__ short f2bf(float f) {
    __bf16 h = (__bf16)f;
    return __builtin_bit_cast(short, h);
}

// ---------------- prep kernels ----------------

// X fp32 -> int8 with per-row symmetric scale (RNE). One block per row.
__global__ __launch_bounds__(256)
void quant_x(const float* __restrict__ X, char* __restrict__ Xq,
             float* __restrict__ sx)
{
    __shared__ float wmax[4];
    const int row = blockIdx.x;
    const float* xr = X + (size_t)row * KDIM;
    const int t = threadIdx.x;
    f32x4 v[4];
    #pragma unroll
    for (int p = 0; p < 4; ++p) v[p] = ((const f32x4*)xr)[t * 4 + p];
    float m = 0.f;
    #pragma unroll
    for (int p = 0; p < 4; ++p)
        #pragma unroll
        for (int q = 0; q < 4; ++q)
            m = fmaxf(m, fabsf(v[p][q]));
    #pragma unroll
    for (int off = 32; off >= 1; off >>= 1)
        m = fmaxf(m, __shfl_xor(m, off));
    if ((t & 63) == 0) wmax[t >> 6] = m;
    __syncthreads();
    m = fmaxf(fmaxf(wmax[0], wmax[1]), fmaxf(wmax[2], wmax[3]));
    const float inv = 127.0f / fmaxf(m, 1e-30f);
    if (t == 0) sx[row] = m * (1.0f / 127.0f);
    int pk[4];
    #pragma unroll
    for (int p = 0; p < 4; ++p) {
        int q0 = min(127, max(-127, __float2int_rn(v[p][0] * inv)));
        int q1 = min(127, max(-127, __float2int_rn(v[p][1] * inv)));
        int q2 = min(127, max(-127, __float2int_rn(v[p][2] * inv)));
        int q3 = min(127, max(-127, __float2int_rn(v[p][3] * inv)));
        pk[p] = (q0 & 255) | ((q1 & 255) << 8) | ((q2 & 255) << 16) | ((q3 & 255) << 24);
    }
    ((i32x4*)(Xq + (size_t)row * KDIM))[t] = *(i32x4*)pk;
}

// W int32 (values in [-127,127]) -> int8 pack, 16 els/thread/iter
__global__ __launch_bounds__(256)
void pack_w(const int* __restrict__ in, char* __restrict__ out, int n16)
{
    for (int i = blockIdx.x * blockDim.x + threadIdx.x; i < n16;
         i += gridDim.x * blockDim.x) {
        int pk[4];
        #pragma unroll
        for (int p = 0; p < 4; ++p) {
            i32x4 a = ((const i32x4*)in)[i * 4 + p];
            pk[p] = (a[0] & 255) | ((a[1] & 255) << 8) |
                    ((a[2] & 255) << 16) | ((a[3] & 255) << 24);
        }
        ((i32x4*)out)[i] = *(i32x4*)pk;
    }
}

// -------- 128x128 int8 GEMM, NO LDS: direct-from-L2 fragments --------------
// After R13, both operand tiles are L2-resident (A: XCD-static 4 MB slab;
// B: ~1-6 MB concurrent panels shared per XCD). R14's ledger showed the
// per-CU LDS pipe (~67 MB frag reads + DMA writes) was the largest consumer.
// R15 removes LDS entirely: each wave owns a 64x64 output tile; fragments
// load straight global->reg. Lane (fr=lane&15, fs=lane>>4) reads the 16 B at
// (row = base+fr, k = kt*64+fs*16): one global_load_dwordx4 per fragment
// touches 16 fully-consumed 64 B cache lines. Operand content is identical
// to R12/R14's verified LDS path (same logical (row,k-slot) per lane; A and
// B share the packing so any internal k-permutation cancels). Cross-tile
// register double-buffer: issue kt+1's 8 loads, then MFMA kt's fragments --
// the compiler inserts the counted vmcnt automatically (G7). No barriers,
// no inter-wave hazards; waves free-run, hiding L2 latency (~200 cyc) under
// the ~320 SIMD-cyc MFMA stretch with 3 waves/SIMD.

__global__ __launch_bounds__(256, 3)
void sl_gemm_i8d(const char* __restrict__ A, const char* __restrict__ Bw,
                 const float* __restrict__ sx,
                 const float* __restrict__ scale_p, const float* __restrict__ bias,
                 float* __restrict__ Out)
{
    const int t    = threadIdx.x;
    const int lane = t & 63;
    const int wave = t >> 6;        // 0..3
    const int wr   = wave >> 1;     // 2x2 wave grid over the 128x128 tile
    const int wc   = wave & 1;      //   (waves pair-share A-rows / B-rows via L1)

    // ---- tile mapping (R13/R14 verbatim): XCD x = bid&7 statically owns
    //      A rows [x*1024, x*1024+1024) = 4 MB i8 -> L2-resident slab.
    int bid = blockIdx.x;                       // 8192 blocks (64 tm x 128 tn)
    int tm = ((bid & 7) << 3) + ((bid >> 3) & 7);
    int tn = bid >> 6;
    const int m0 = tm << 7;
    const int n0 = tn << 7;

    const int fr = lane & 15;
    const int fs = lane >> 4;                              // 0..3

    // per-lane fragment base pointers (frag i at + i*16*KDIM, kt at + kt*64)
    const char* pA = A  + (size_t)(m0 + wr * 64 + fr) * KDIM + fs * 16;
    const char* pB = Bw + (size_t)(n0 + wc * 64 + fr) * KDIM + fs * 16;

    i32x4 acc[4][4];
    #pragma unroll
    for (int i = 0; i < 4; ++i)
        #pragma unroll
        for (int j = 0; j < 4; ++j)
            acc[i][j] = (i32x4){0, 0, 0, 0};

    i32x4 FA[4], FB[4], GA[4], GB[4];

    // prologue: fragments of K-tile 0
    #pragma unroll
    for (int i = 0; i < 4; ++i)
        FA[i] = *(const i32x4*)(pA + (size_t)i * 16 * KDIM);
    #pragma unroll
    for (int j = 0; j < 4; ++j)
        FB[j] = *(const i32x4*)(pB + (size_t)j * 16 * KDIM);

    #define HALF(CUR_A, CUR_B, NXT_A, NXT_B, KT)                               \
    {                                                                          \
        const size_t ko = (size_t)(((KT) + 1) & (NKT - 1)) * 64;               \
        _Pragma("unroll")                                                      \
        for (int i = 0; i < 4; ++i)                                            \
            NXT_A[i] = *(const i32x4*)(pA + ko + (size_t)i * 16 * KDIM);       \
        _Pragma("unroll")                                                      \
        for (int j = 0; j < 4; ++j)                                            \
            NXT_B[j] = *(const i32x4*)(pB + ko + (size_t)j * 16 * KDIM);       \
        _Pragma("unroll")                                                      \
        for (int i = 0; i < 4; ++i)                                            \
            _Pragma("unroll")                                                  \
            for (int j = 0; j < 4; ++j)                                        \
                acc[i][j] = __builtin_amdgcn_mfma_i32_16x16x64_i8(             \
                    CUR_A[i], CUR_B[j], acc[i][j], 0, 0, 0);                   \
    }

    for (int kt = 0; kt < NKT; kt += 2) {
        HALF(FA, FB, GA, GB, kt);
        HALF(GA, GB, FA, FB, kt + 1);
    }
    #undef HALF

    // ---- epilogue: D col = lane&15, row = fs*4 + q; per-row dequant + bias
    const float scale = scale_p[0];
    #pragma unroll
    for (int i = 0; i < 4; ++i) {
        const int r0 = m0 + wr * 64 + i * 16 + fs * 4;
        float s4[4];
        #pragma unroll
        for (int q = 0; q < 4; ++q) s4[q] = sx[r0 + q] * scale;
        #pragma unroll
        for (int j = 0; j < 4; ++j) {
            const int c   = n0 + wc * 64 + j * 16 + fr;
            const float bj = bias[c];
            float* op = Out + (size_t)r0 * NDIM + c;
            #pragma unroll
            for (int q = 0; q < 4; ++q)
                op[(size_t)q * NDIM] = (float)acc[i][j][q] * s4[q] + bj;
        }
    }
}

// ---------------- fallback (fp32 direct, no workspace) ----------------

__global__ __launch_bounds__(256, 2)
void sl_gemm_fb(const float* __restrict__ X, const int* __restrict__ Wq,
                const float* __restrict__ scale_p, const float* __restrict__ bias,
                float* __restrict__ Out)
{
    __shared__ s16x8 As[128 * 4];
    __shared__ s16x8 Bs[128 * 4];

    const int t    = threadIdx.x;
    const int lane = t & 63;
    const int wave = t >> 6;
    const int wr   = wave >> 1;
    const int wc   = wave & 1;

    int bid = blockIdx.x;
    int swz = (bid & 7) * 1024 + (bid >> 3);
    int panel   = swz >> 10;
    int inpanel = swz & 1023;
    int tn = (panel << 4) + (inpanel >> 6);
    int tm = inpanel & 63;
    const int m0 = tm << 7;
    const int n0 = tn << 7;

    const int srow  = t >> 1;
    const int shalf = t & 1;
    const float* Xp = X  + (size_t)(m0 + srow) * KDIM + shalf * 16;
    const int*   Wp = Wq + (size_t)(n0 + srow) * KDIM + shalf * 16;

    f32x4 acc[4][4];
    #pragma unroll
    for (int i = 0; i < 4; ++i)
        #pragma unroll
        for (int j = 0; j < 4; ++j)
            acc[i][j] = (f32x4){0.f, 0.f, 0.f, 0.f};

    const int fr = lane & 15;
    const int fs = lane >> 4;

    f32x4 ar[4];
    i32x4 br[4];
    #pragma unroll
    for (int p = 0; p < 4; ++p) {
        ar[p] = *(const f32x4*)(Xp + p * 4);
        br[p] = *(const i32x4*)(Wp + p * 4);
    }

    const int wbase = srow * 4;
    const int wswz  = (srow >> 1) & 3;
    const int ws0   = (shalf * 2)     ^ wswz;
    const int ws1   = (shalf * 2 + 1) ^ wswz;

    for (int kt = 0; kt < KDIM / 32; ++kt) {
        __syncthreads();
        {
            s16x8 v0, v1;
            #pragma unroll
            for (int q = 0; q < 8; ++q) v0[q] = f2bf(ar[q >> 2][q & 3]);
            #pragma unroll
            for (int q = 0; q < 8; ++q) v1[q] = f2bf(ar[2 + (q >> 2)][q & 3]);
            As[wbase + ws0] = v0;
            As[wbase + ws1] = v1;
            s16x8 u0, u1;
            #pragma unroll
            for (int q = 0; q < 8; ++q) u0[q] = f2bf((float)br[q >> 2][q & 3]);
            #pragma unroll
            for (int q = 0; q < 8; ++q) u1[q] = f2bf((float)br[2 + (q >> 2)][q & 3]);
            Bs[wbase + ws0] = u0;
            Bs[wbase + ws1] = u1;
        }
        __syncthreads();

        if (kt + 1 < KDIM / 32) {
            const float* Xn = Xp + (size_t)(kt + 1) * 32;
            const int*   Wn = Wp + (size_t)(kt + 1) * 32;
            #pragma unroll
            for (int p = 0; p < 4; ++p) {
                ar[p] = *(const f32x4*)(Xn + p * 4);
                br[p] = *(const i32x4*)(Wn + p * 4);
            }
        }

        s16x8 af[4], bq[4];
        #pragma unroll
        for (int i = 0; i < 4; ++i) {
            int row = wr * 64 + i * 16 + fr;
            af[i] = As[row * 4 + (fs ^ ((row >> 1) & 3))];
        }
        #pragma unroll
        for (int j = 0; j < 4; ++j) {
            int col = wc * 64 + j * 16 + fr;
            bq[j] = Bs[col * 4 + (fs ^ ((col >> 1) & 3))];
        }
        #pragma unroll
        for (int i = 0; i < 4; ++i)
            #pragma unroll
            for (int j = 0; j < 4; ++j)
                acc[i][j] = __builtin_amdgcn_mfma_f32_16x16x32_bf16(
                    af[i], bq[j], acc[i][j], 0, 0, 0);
    }

    const float scale = scale_p[0];
    #pragma unroll
    for (int j = 0; j < 4; ++j) {
        const int c  = n0 + wc * 64 + j * 16 + fr;
        const float bj = bias[c];
        #pragma unroll
        for (int i = 0; i < 4; ++i) {
            const int r0 = m0 + wr * 64 + i * 16 + fs * 4;
            float* op = Out + (size_t)r0 * NDIM + c;
            #pragma unroll
            for (int q = 0; q < 4; ++q)
                op[(size_t)q * NDIM] = acc[i][j][q] * scale + bj;
        }
    }
}

extern "C" void kernel_launch(void* const* d_in, const int* in_sizes, int n_in,
                              void* d_out, int out_size, void* d_ws, size_t ws_size,
                              hipStream_t stream) {
    const float* X     = (const float*)d_in[0];
    const int*   Wq    = (const int*)d_in[1];   // int8 widened to int32 by harness
    const float* scale = (const float*)d_in[2];
    const float* bias  = (const float*)d_in[3];
    float*       Out   = (float*)d_out;

    const size_t xqB = (size_t)MDIM * KDIM;          // 33.5 MB
    const size_t wqB = (size_t)NDIM * KDIM;          // 67 MB
    const size_t sxB = (size_t)MDIM * sizeof(float); // 32 KB
    if (ws_size >= xqB + wqB + sxB) {
        char*  Xq  = (char*)d_ws;
        char*  Wq8 = (char*)d_ws + xqB;
        float* sx  = (float*)((char*)d_ws + xqB + wqB);
        hipLaunchKernelGGL(quant_x, dim3(MDIM), dim3(256), 0, stream, X, Xq, sx);
        hipLaunchKernelGGL(pack_w, dim3(2048), dim3(256), 0, stream,
                           Wq, Wq8, NDIM * KDIM / 16);
        hipLaunchKernelGGL(sl_gemm_i8d, dim3(8192), dim3(256), 0, stream,
                           Xq, Wq8, sx, scale, bias, Out);
    } else {
        hipLaunchKernelGGL(sl_gemm_fb, dim3(8192), dim3(256), 0, stream,
                           X, Wq, scale, bias, Out);
    }
}

// Round 16
// 884.731 us; speedup vs baseline: 2.1733x; 2.1733x over previous
//
#include <hip/hip_runtime.h>
#include <hip/hip_bf16.h>

typedef __attribute__((ext_vector_type(4))) float f32x4;
typedef __attribute__((ext_vector_type(4))) int   i32x4;
typedef __attribute__((ext_vector_type(8))) short s16x8;
typedef unsigned short ushort_t;

#define MDIM 8192
#define KDIM 4096
#define NDIM 16384
#define NKT  64                 // 64 K-tiles of 64 int8 elems

static __device__ __forceinline__ short f2bf(float f) {
    __bf16 h = (__bf16)f;
    return __builtin_bit_cast(short, h);
}

static __device__ __forceinline__ void gload_lds16(const void* g, void* l) {
    __builtin_amdgcn_global_load_lds(
        (const __attribute__((address_space(1))) unsigned int*)g,
        (__attribute__((address_space(3))) unsigned int*)l,
        16, 0, 0);
}

// ---------------- prep kernels ----------------

// X fp32 -> int8 with per-row symmetric scale (RNE). One block per row.
__global__ __launch_bounds__(256)
void quant_x(const float* __restrict__ X, char* __restrict__ Xq,
             float* __restrict__ sx)
{
    __shared__ float wmax[4];
    const int row = blockIdx.x;
    const float* xr = X + (size_t)row * KDIM;
    const int t = threadIdx.x;
    f32x4 v[4];
    #pragma unroll
    for (int p = 0; p < 4; ++p) v[p] = ((const f32x4*)xr)[t * 4 + p];
    float m = 0.f;
    #pragma unroll
    for (int p = 0; p < 4; ++p)
        #pragma unroll
        for (int q = 0; q < 4; ++q)
            m = fmaxf(m, fabsf(v[p][q]));
    #pragma unroll
    for (int off = 32; off >= 1; off >>= 1)
        m = fmaxf(m, __shfl_xor(m, off));
    if ((t & 63) == 0) wmax[t >> 6] = m;
    __syncthreads();
    m = fmaxf(fmaxf(wmax[0], wmax[1]), fmaxf(wmax[2], wmax[3]));
    const float inv = 127.0f / fmaxf(m, 1e-30f);
    if (t == 0) sx[row] = m * (1.0f / 127.0f);
    int pk[4];
    #pragma unroll
    for (int p = 0; p < 4; ++p) {
        int q0 = min(127, max(-127, __float2int_rn(v[p][0] * inv)));
        int q1 = min(127, max(-127, __float2int_rn(v[p][1] * inv)));
        int q2 = min(127, max(-127, __float2int_rn(v[p][2] * inv)));
        int q3 = min(127, max(-127, __float2int_rn(v[p][3] * inv)));
        pk[p] = (q0 & 255) | ((q1 & 255) << 8) | ((q2 & 255) << 16) | ((q3 & 255) << 24);
    }
    ((i32x4*)(Xq + (size_t)row * KDIM))[t] = *(i32x4*)pk;
}

// W int32 (values in [-127,127]) -> int8 pack, 16 els/thread/iter
__global__ __launch_bounds__(256)
void pack_w(const int* __restrict__ in, char* __restrict__ out, int n16)
{
    for (int i = blockIdx.x * blockDim.x + threadIdx.x; i < n16;
         i += gridDim.x * blockDim.x) {
        int pk[4];
        #pragma unroll
        for (int p = 0; p < 4; ++p) {
            i32x4 a = ((const i32x4*)in)[i * 4 + p];
            pk[p] = (a[0] & 255) | ((a[1] & 255) << 8) |
                    ((a[2] & 255) << 16) | ((a[3] & 255) << 24);
        }
        ((i32x4*)out)[i] = *(i32x4*)pk;
    }
}

// ------ 128x128 int8 GEMM, ring-4 LDS, cross-tile reg dbuf, 2 blocks/CU ----
// R16 = R14 geometry + R12's verified cross-tile register double-buffer:
//   MFMAs at iter it consume registers loaded at iter it-1 (zero post-barrier
//   LDS dependency); this iter's 8 ds_reads (tile it+1, buf (it+1)&3) and 4
//   staging calls (tile it+3 -> buf (it+3)&3) issue under the MFMA shadow.
//   Trailing {vmcnt(4); s_barrier; sched_barrier(0)} per K-tile, never 0:
//   at iter it's trailing wait, outstanding = own 4 calls (tile it+3);
//   iter it-1's calls (tile it+2) drained -> buf for iter it+1's reads is
//   published. WAR: buf (it+3)&3 holds tile it-1 whose last ds_reads fed
//   MFMAs at iter it-1, i.e. completed before the previous trailing barrier.
//   (Identical ledger to R12, which passed refcheck twice at 256^2.)
// Levers retained: i8 MFMA (R12), XCD-static A-slab (R13), multi-block
// co-residency (R14): ring-4 x 16 KB = 64 KB LDS -> 2 blocks/CU.
// Byte geometry verbatim R14: rows 64 B = 4 slots of 16 B; phys slot =
// logical ^ ((row>>1)&3); swizzle on the GLOBAL source addr, LDS dest linear.

#define BAR()   __builtin_amdgcn_s_barrier()
#define SB0()   __builtin_amdgcn_sched_barrier(0)
#define PRIO(N) __builtin_amdgcn_s_setprio(N)

#define KTILE(CA, CB, NA, NB, IT, RB, WB)                                      \
  {                                                                            \
    const char* rbuf = ldsc + (RB);                                            \
    char*       wbuf = ldsc + (WB);                                            \
    const size_t ko  = (size_t)(((IT) + 3) & (NKT - 1)) * 64;                  \
    _Pragma("unroll")                                                          \
    for (int j = 0; j < 4; ++j) NB[j] = *(const i32x4*)(rbuf + boff[j]);       \
    _Pragma("unroll")                                                          \
    for (int i = 0; i < 2; ++i) NA[i] = *(const i32x4*)(rbuf + aoff[i]);       \
    gload_lds16(pA0 + ko, wbuf + 0    + ldsw);                                 \
    gload_lds16(pA1 + ko, wbuf + 4096 + ldsw);                                 \
    SB0();                                                                     \
    PRIO(1);                                                                   \
    _Pragma("unroll")                                                          \
    for (int m = 0; m < 2; ++m)                                                \
      _Pragma("unroll")                                                        \
      for (int nn = 0; nn < 4; ++nn)                                           \
        acc[m][nn] = __builtin_amdgcn_mfma_i32_16x16x64_i8(                    \
            CA[m], CB[nn], acc[m][nn], 0, 0, 0);                               \
    PRIO(0);                                                                   \
    _Pragma("unroll")                                                          \
    for (int i = 2; i < 4; ++i) NA[i] = *(const i32x4*)(rbuf + aoff[i]);       \
    gload_lds16(pB0 + ko, wbuf + 8192  + ldsw);                                \
    gload_lds16(pB1 + ko, wbuf + 12288 + ldsw);                                \
    SB0();                                                                     \
    PRIO(1);                                                                   \
    _Pragma("unroll")                                                          \
    for (int m = 2; m < 4; ++m)                                                \
      _Pragma("unroll")                                                        \
      for (int nn = 0; nn < 4; ++nn)                                           \
        acc[m][nn] = __builtin_amdgcn_mfma_i32_16x16x64_i8(                    \
            CA[m], CB[nn], acc[m][nn], 0, 0, 0);                               \
    PRIO(0);                                                                   \
    asm volatile("s_waitcnt vmcnt(4)" ::: "memory");   /* counted, never 0 */  \
    BAR();                                                                     \
    SB0();                                                                     \
  }

__global__ __launch_bounds__(256, 2)
void sl_gemm_i8r(const char* __restrict__ A, const char* __restrict__ Bw,
                 const float* __restrict__ sx,
                 const float* __restrict__ scale_p, const float* __restrict__ bias,
                 float* __restrict__ Out)
{
    __shared__ char ldsbuf[65536];   // 4 bufs x (A 8 KB + B 8 KB)
    char* ldsc = ldsbuf;

    const int t    = threadIdx.x;
    const int lane = t & 63;
    const int wave = t >> 6;        // 0..3
    const int wr   = wave >> 1;     // 0..1 : 64 output rows each
    const int wc   = wave & 1;      // 0..1 : 64 output cols each

    // ---- tile mapping (R13/R14 verbatim): XCD x = bid&7 statically owns
    //      A rows [x*1024, x*1024+1024) = 4 MB i8 -> L2-resident slab.
    int bid = blockIdx.x;                       // 8192 blocks (64 tm x 128 tn)
    int tm = ((bid & 7) << 3) + ((bid >> 3) & 7);
    int tn = bid >> 6;
    const int m0 = tm << 7;
    const int n0 = tn << 7;

    // ---- staging geometry (verbatim R14): per 4 KB call (64 rows), thread
    //      covers row c*64 + (t>>2), physical slot t&3; logical slot =
    //      phys ^ ((row>>1)&3)
    const int srow  = t >> 2;                             // 0..63
    const int sslot = t & 3;
    const int sA    = sslot ^ ((srow >> 1) & 3);
    const char* pA0 = A  + (size_t)(m0 + srow) * KDIM + sA * 16;
    const char* pA1 = pA0 + (size_t)64 * KDIM;
    const char* pB0 = Bw + (size_t)(n0 + srow) * KDIM + sA * 16;
    const char* pB1 = pB0 + (size_t)64 * KDIM;
    const int ldsw = wave * 1024;                          // wave-uniform dest

    // ---- fragment read offsets (byte, buf-relative; verbatim R14)
    const int fr = lane & 15;
    const int fs = lane >> 4;                              // 0..3
    int aoff[4], boff[4];
    #pragma unroll
    for (int i = 0; i < 4; ++i) {
        int ra = wr * 64 + i * 16 + fr;                    // 0..127
        aoff[i] = ra * 64 + ((fs ^ ((ra >> 1) & 3)) * 16);
    }
    #pragma unroll
    for (int j = 0; j < 4; ++j) {
        int rb = wc * 64 + j * 16 + fr;                    // 0..127
        boff[j] = 8192 + rb * 64 + ((fs ^ ((rb >> 1) & 3)) * 16);
    }

    i32x4 acc[4][4];
    #pragma unroll
    for (int i = 0; i < 4; ++i)
        #pragma unroll
        for (int j = 0; j < 4; ++j)
            acc[i][j] = (i32x4){0, 0, 0, 0};

    // ---- prologue: stage tiles 0,1,2 -> bufs 0,1,2 (4 calls each)
    #pragma unroll
    for (int kt = 0; kt < 3; ++kt) {
        const size_t ko = (size_t)kt * 64;
        char* b = ldsc + kt * 16384;
        gload_lds16(pA0 + ko, b + 0     + ldsw);
        gload_lds16(pA1 + ko, b + 4096  + ldsw);
        gload_lds16(pB0 + ko, b + 8192  + ldsw);
        gload_lds16(pB1 + ko, b + 12288 + ldsw);
    }
    asm volatile("s_waitcnt vmcnt(4)" ::: "memory");   // tiles 0,1 landed
    BAR();
    SB0();

    // R_cur <- tile 0 fragments (buf 0)
    i32x4 FA[4], FB[4], GA[4], GB[4];
    #pragma unroll
    for (int i = 0; i < 4; ++i) FA[i] = *(const i32x4*)(ldsc + aoff[i]);
    #pragma unroll
    for (int j = 0; j < 4; ++j) FB[j] = *(const i32x4*)(ldsc + boff[j]);

    // ring positions mod 4 compile-time per unrolled slot:
    //   slot p: read buf (p+1)&3 (tile p+1), write buf (p+3)&3 (tile p+3)
    for (int it = 0; it < NKT; it += 4) {
        KTILE(FA, FB, GA, GB, it + 0, 1 * 16384, 3 * 16384);
        KTILE(GA, GB, FA, FB, it + 1, 2 * 16384, 0 * 16384);
        KTILE(FA, FB, GA, GB, it + 2, 3 * 16384, 1 * 16384);
        KTILE(GA, GB, FA, FB, it + 3, 0 * 16384, 2 * 16384);
    }

    // ---- epilogue: D col = lane&15, row = fs*4 + q; per-row dequant + bias
    const float scale = scale_p[0];
    #pragma unroll
    for (int i = 0; i < 4; ++i) {
        const int r0 = m0 + wr * 64 + i * 16 + fs * 4;
        float s4[4];
        #pragma unroll
        for (int q = 0; q < 4; ++q) s4[q] = sx[r0 + q] * scale;
        #pragma unroll
        for (int j = 0; j < 4; ++j) {
            const int c   = n0 + wc * 64 + j * 16 + fr;
            const float bj = bias[c];
            float* op = Out + (size_t)r0 * NDIM + c;
            #pragma unroll
            for (int q = 0; q < 4; ++q)
                op[(size_t)q * NDIM] = (float)acc[i][j][q] * s4[q] + bj;
        }
    }
}

// ---------------- fallback (fp32 direct, no workspace) ----------------

__global__ __launch_bounds__(256, 2)
void sl_gemm_fb(const float* __restrict__ X, const int* __restrict__ Wq,
                const float* __restrict__ scale_p, const float* __restrict__ bias,
                float* __restrict__ Out)
{
    __shared__ s16x8 As[128 * 4];
    __shared__ s16x8 Bs[128 * 4];

    const int t    = threadIdx.x;
    const int lane = t & 63;
    const int wave = t >> 6;
    const int wr   = wave >> 1;
    const int wc   = wave & 1;

    int bid = blockIdx.x;
    int swz = (bid & 7) * 1024 + (bid >> 3);
    int panel   = swz >> 10;
    int inpanel = swz & 1023;
    int tn = (panel << 4) + (inpanel >> 6);
    int tm = inpanel & 63;
    const int m0 = tm << 7;
    const int n0 = tn << 7;

    const int srow  = t >> 1;
    const int shalf = t & 1;
    const float* Xp = X  + (size_t)(m0 + srow) * KDIM + shalf * 16;
    const int*   Wp = Wq + (size_t)(n0 + srow) * KDIM + shalf * 16;

    f32x4 acc[4][4];
    #pragma unroll
    for (int i = 0; i < 4; ++i)
        #pragma unroll
        for (int j = 0; j < 4; ++j)
            acc[i][j] = (f32x4){0.f, 0.f, 0.f, 0.f};

    const int fr = lane & 15;
    const int fs = lane >> 4;

    f32x4 ar[4];
    i32x4 br[4];
    #pragma unroll
    for (int p = 0; p < 4; ++p) {
        ar[p] = *(const f32x4*)(Xp + p * 4);
        br[p] = *(const i32x4*)(Wp + p * 4);
    }

    const int wbase = srow * 4;
    const int wswz  = (srow >> 1) & 3;
    const int ws0   = (shalf * 2)     ^ wswz;
    const int ws1   = (shalf * 2 + 1) ^ wswz;

    for (int kt = 0; kt < KDIM / 32; ++kt) {
        __syncthreads();
        {
            s16x8 v0, v1;
            #pragma unroll
            for (int q = 0; q < 8; ++q) v0[q] = f2bf(ar[q >> 2][q & 3]);
            #pragma unroll
            for (int q = 0; q < 8; ++q) v1[q] = f2bf(ar[2 + (q >> 2)][q & 3]);
            As[wbase + ws0] = v0;
            As[wbase + ws1] = v1;
            s16x8 u0, u1;
            #pragma unroll
            for (int q = 0; q < 8; ++q) u0[q] = f2bf((float)br[q >> 2][q & 3]);
            #pragma unroll
            for (int q = 0; q < 8; ++q) u1[q] = f2bf((float)br[2 + (q >> 2)][q & 3]);
            Bs[wbase + ws0] = u0;
            Bs[wbase + ws1] = u1;
        }
        __syncthreads();

        if (kt + 1 < KDIM / 32) {
            const float* Xn = Xp + (size_t)(kt + 1) * 32;
            const int*   Wn = Wp + (size_t)(kt + 1) * 32;
            #pragma unroll
            for (int p = 0; p < 4; ++p) {
                ar[p] = *(const f32x4*)(Xn + p * 4);
                br[p] = *(const i32x4*)(Wn + p * 4);
            }
        }

        s16x8 af[4], bq[4];
        #pragma unroll
        for (int i = 0; i < 4; ++i) {
            int row = wr * 64 + i * 16 + fr;
            af[i] = As[row * 4 + (fs ^ ((row >> 1) & 3))];
        }
        #pragma unroll
        for (int j = 0; j < 4; ++j) {
            int col = wc * 64 + j * 16 + fr;
            bq[j] = Bs[col * 4 + (fs ^ ((col >> 1) & 3))];
        }
        #pragma unroll
        for (int i = 0; i < 4; ++i)
            #pragma unroll
            for (int j = 0; j < 4; ++j)
                acc[i][j] = __builtin_amdgcn_mfma_f32_16x16x32_bf16(
                    af[i], bq[j], acc[i][j], 0, 0, 0);
    }

    const float scale = scale_p[0];
    #pragma unroll
    for (int j = 0; j < 4; ++j) {
        const int c  = n0 + wc * 64 + j * 16 + fr;
        const float bj = bias[c];
        #pragma unroll
        for (int i = 0; i < 4; ++i) {
            const int r0 = m0 + wr * 64 + i * 16 + fs * 4;
            float* op = Out + (size_t)r0 * NDIM + c;
            #pragma unroll
            for (int q = 0; q < 4; ++q)
                op[(size_t)q * NDIM] = acc[i][j][q] * scale + bj;
        }
    }
}

extern "C" void kernel_launch(void* const* d_in, const int* in_sizes, int n_in,
                              void* d_out, int out_size, void* d_ws, size_t ws_size,
                              hipStream_t stream) {
    const float* X     = (const float*)d_in[0];
    const int*   Wq    = (const int*)d_in[1];   // int8 widened to int32 by harness
    const float* scale = (const float*)d_in[2];
    const float* bias  = (const float*)d_in[3];
    float*       Out   = (float*)d_out;

    const size_t xqB = (size_t)MDIM * KDIM;          // 33.5 MB
    const size_t wqB = (size_t)NDIM * KDIM;          // 67 MB
    const size_t sxB = (size_t)MDIM * sizeof(float); // 32 KB
    if (ws_size >= xqB + wqB + sxB) {
        char*  Xq  = (char*)d_ws;
        char*  Wq8 = (char*)d_ws + xqB;
        float* sx  = (float*)((char*)d_ws + xqB + wqB);
        hipLaunchKernelGGL(quant_x, dim3(MDIM), dim3(256), 0, stream, X, Xq, sx);
        hipLaunchKernelGGL(pack_w, dim3(2048), dim3(256), 0, stream,
                           Wq, Wq8, NDIM * KDIM / 16);
        hipLaunchKernelGGL(sl_gemm_i8r, dim3(8192), dim3(256), 0, stream,
                           Xq, Wq8, sx, scale, bias, Out);
    } else {
        hipLaunchKernelGGL(sl_gemm_fb, dim3(8192), dim3(256), 0, stream,
                           X, Wq, scale, bias, Out);
    }
}

// Round 17
// 655.728 us; speedup vs baseline: 2.9323x; 1.3492x over previous
//
#include <hip/hip_runtime.h>
#include <hip/hip_bf16.h>

typedef __attribute__((ext_vector_type(4))) float f32x4;
typedef __attribute__((ext_vector_type(4))) int   i32x4;
typedef __attribute__((ext_vector_type(8))) short s16x8;
typedef unsigned short ushort_t;

#define MDIM 8192
#define KDIM 4096
#define NDIM 16384
#define NKT  64                 // 64 K-tiles of 64 int8 elems

static __device__ __forceinline__ short f2bf(float f) {
    __bf16 h = (__bf16)f;
    return __builtin_bit_cast(short, h);
}

static __device__ __forceinline__ void gload_lds16(const void* g, void* l) {
    __builtin_amdgcn_global_load_lds(
        (const __attribute__((address_space(1))) unsigned int*)g,
        (__attribute__((address_space(3))) unsigned int*)l,
        16, 0, 0);
}

// ---------------- prep kernels ----------------

// X fp32 -> int8 with per-row symmetric scale (RNE). One block per row.
__global__ __launch_bounds__(256)
void quant_x(const float* __restrict__ X, char* __restrict__ Xq,
             float* __restrict__ sx)
{
    __shared__ float wmax[4];
    const int row = blockIdx.x;
    const float* xr = X + (size_t)row * KDIM;
    const int t = threadIdx.x;
    f32x4 v[4];
    #pragma unroll
    for (int p = 0; p < 4; ++p) v[p] = ((const f32x4*)xr)[t * 4 + p];
    float m = 0.f;
    #pragma unroll
    for (int p = 0; p < 4; ++p)
        #pragma unroll
        for (int q = 0; q < 4; ++q)
            m = fmaxf(m, fabsf(v[p][q]));
    #pragma unroll
    for (int off = 32; off >= 1; off >>= 1)
        m = fmaxf(m, __shfl_xor(m, off));
    if ((t & 63) == 0) wmax[t >> 6] = m;
    __syncthreads();
    m = fmaxf(fmaxf(wmax[0], wmax[1]), fmaxf(wmax[2], wmax[3]));
    const float inv = 127.0f / fmaxf(m, 1e-30f);
    if (t == 0) sx[row] = m * (1.0f / 127.0f);
    int pk[4];
    #pragma unroll
    for (int p = 0; p < 4; ++p) {
        int q0 = min(127, max(-127, __float2int_rn(v[p][0] * inv)));
        int q1 = min(127, max(-127, __float2int_rn(v[p][1] * inv)));
        int q2 = min(127, max(-127, __float2int_rn(v[p][2] * inv)));
        int q3 = min(127, max(-127, __float2int_rn(v[p][3] * inv)));
        pk[p] = (q0 & 255) | ((q1 & 255) << 8) | ((q2 & 255) << 16) | ((q3 & 255) << 24);
    }
    ((i32x4*)(Xq + (size_t)row * KDIM))[t] = *(i32x4*)pk;
}

// W int32 (values in [-127,127]) -> int8 pack, 16 els/thread/iter
__global__ __launch_bounds__(256)
void pack_w(const int* __restrict__ in, char* __restrict__ out, int n16)
{
    for (int i = blockIdx.x * blockDim.x + threadIdx.x; i < n16;
         i += gridDim.x * blockDim.x) {
        int pk[4];
        #pragma unroll
        for (int p = 0; p < 4; ++p) {
            i32x4 a = ((const i32x4*)in)[i * 4 + p];
            pk[p] = (a[0] & 255) | ((a[1] & 255) << 8) |
                    ((a[2] & 255) << 16) | ((a[3] & 255) << 24);
        }
        ((i32x4*)out)[i] = *(i32x4*)pk;
    }
}

// ---- 256x256 int8 GEMM, faithful 8-phase + ring-4 + counted waits ---------
// Per iter (tiles T=2i ph0-3, T+1 ph4-7), each phase:
//   [2-6 ds_reads for NEXT phase][1 gload] BAR lgkmcnt(N) SB0
//   setprio(1) 8 MFMA setprio(0) [vmcnt(7) at ph2/ph6] BAR
// Counted waits only (never 0 in-loop):
//   lgkm(N): N = this phase's own reads -> drains previous phase's reads.
//   vmcnt(7) at ph2: 7 newest = {iter i ph0-2 (3), iter i-1 ph4-7 (4)} ->
//     tile 2i+1 (iter i-1 ph0-3) drained; published by ph2's BAR for ph3.
//   vmcnt(7) at ph6: 7 newest = {iter i ph4-6 (3), ph0-3 (4)} -> tile 2i+2
//     (iter i-1 ph4-7) drained; published for ph7's reads.
// WAR: W0 buf's last reader drained by prior iter's ph7 lgkm before its
// trailing BAR; W1 (= R0) last read at ph2, proven done by ph3's lgkm(6),
// staged from ph4 (after ph3's barriers). Ledger checked for all waves.
// Levers retained: i8 MFMA (R12), XCD-static A-slab (R13). Byte geometry
// (staging, swizzle, frag offsets) verbatim R12 (verified).

#define BAR()   __builtin_amdgcn_s_barrier()
#define SB0()   __builtin_amdgcn_sched_barrier(0)
#define PRIO(N) __builtin_amdgcn_s_setprio(N)
#define LGKM2() do { asm volatile("s_waitcnt lgkmcnt(2)" ::: "memory"); SB0(); } while (0)
#define LGKM6() do { asm volatile("s_waitcnt lgkmcnt(6)" ::: "memory"); SB0(); } while (0)
#define VM7()   asm volatile("s_waitcnt vmcnt(7)" ::: "memory")

#define MM8(M0, PA, PB)                                                        \
    PRIO(1);                                                                   \
    _Pragma("unroll")                                                          \
    for (int nn = 0; nn < 4; ++nn)                                             \
        acc[M0][nn] = __builtin_amdgcn_mfma_i32_16x16x64_i8(                   \
            PA[0], PB[nn], acc[M0][nn], 0, 0, 0);                              \
    _Pragma("unroll")                                                          \
    for (int nn = 0; nn < 4; ++nn)                                             \
        acc[(M0) + 1][nn] = __builtin_amdgcn_mfma_i32_16x16x64_i8(             \
            PA[1], PB[nn], acc[(M0) + 1][nn], 0, 0, 0);                        \
    PRIO(0);

#define ITER(RB0, RB1, RB2, WB0, WB1, T)                                       \
  {                                                                            \
    const char* r0 = ldsc + (RB0);                                             \
    const char* r1 = ldsc + (RB1);                                             \
    const char* r2 = ldsc + (RB2);                                             \
    char* w0 = ldsc + (WB0);                                                   \
    char* w1 = ldsc + (WB1);                                                   \
    const size_t ko3 = (size_t)(((T) + 3) & (NKT - 1)) * 64;                   \
    const size_t ko4 = (size_t)(((T) + 4) & (NKT - 1)) * 64;                   \
    /* ph0: uses PA0(frags0,1 tile T)+BF; loads PA1<-frags2,3 */               \
    PA1[0] = *(const i32x4*)(r0 + aoff[2]);                                    \
    PA1[1] = *(const i32x4*)(r0 + aoff[3]);                                    \
    gload_lds16(pA0 + ko3, w0 + 0 + ldsw);                                     \
    BAR(); LGKM2(); MM8(0, PA0, BF); BAR();                                    \
    /* ph1 */                                                                  \
    PA0[0] = *(const i32x4*)(r0 + aoff[4]);                                    \
    PA0[1] = *(const i32x4*)(r0 + aoff[5]);                                    \
    gload_lds16(pA1 + ko3, w0 + 8192 + ldsw);                                  \
    BAR(); LGKM2(); MM8(2, PA1, BF); BAR();                                    \
    /* ph2: vmcnt(7) publishes tile T+1 for ph3's reads */                     \
    PA1[0] = *(const i32x4*)(r0 + aoff[6]);                                    \
    PA1[1] = *(const i32x4*)(r0 + aoff[7]);                                    \
    gload_lds16(pB0 + ko3, w0 + 16384 + ldsw);                                 \
    BAR(); LGKM2(); MM8(4, PA0, BF); VM7(); BAR();                             \
    /* ph3: loads next tile's B + A0,1 */                                      \
    BG[0] = *(const i32x4*)(r1 + boff[0]);                                     \
    BG[1] = *(const i32x4*)(r1 + boff[1]);                                     \
    BG[2] = *(const i32x4*)(r1 + boff[2]);                                     \
    BG[3] = *(const i32x4*)(r1 + boff[3]);                                     \
    PA0[0] = *(const i32x4*)(r1 + aoff[0]);                                    \
    PA0[1] = *(const i32x4*)(r1 + aoff[1]);                                    \
    gload_lds16(pB1 + ko3, w0 + 24576 + ldsw);                                 \
    BAR(); LGKM6(); MM8(6, PA1, BF); BAR();                                    \
    /* ph4: tile T+1 */                                                        \
    PA1[0] = *(const i32x4*)(r1 + aoff[2]);                                    \
    PA1[1] = *(const i32x4*)(r1 + aoff[3]);                                    \
    gload_lds16(pA0 + ko4, w1 + 0 + ldsw);                                     \
    BAR(); LGKM2(); MM8(0, PA0, BG); BAR();                                    \
    /* ph5 */                                                                  \
    PA0[0] = *(const i32x4*)(r1 + aoff[4]);                                    \
    PA0[1] = *(const i32x4*)(r1 + aoff[5]);                                    \
    gload_lds16(pA1 + ko4, w1 + 8192 + ldsw);                                  \
    BAR(); LGKM2(); MM8(2, PA1, BG); BAR();                                    \
    /* ph6: vmcnt(7) publishes tile T+2 for ph7's reads */                     \
    PA1[0] = *(const i32x4*)(r1 + aoff[6]);                                    \
    PA1[1] = *(const i32x4*)(r1 + aoff[7]);                                    \
    gload_lds16(pB0 + ko4, w1 + 16384 + ldsw);                                 \
    BAR(); LGKM2(); MM8(4, PA0, BG); VM7(); BAR();                             \
    /* ph7: loads tile T+2's B + A0,1 */                                       \
    BF[0] = *(const i32x4*)(r2 + boff[0]);                                     \
    BF[1] = *(const i32x4*)(r2 + boff[1]);                                     \
    BF[2] = *(const i32x4*)(r2 + boff[2]);                                     \
    BF[3] = *(const i32x4*)(r2 + boff[3]);                                     \
    PA0[0] = *(const i32x4*)(r2 + aoff[0]);                                    \
    PA0[1] = *(const i32x4*)(r2 + aoff[1]);                                    \
    gload_lds16(pB1 + ko4, w1 + 24576 + ldsw);                                 \
    BAR(); LGKM6(); MM8(6, PA1, BG); BAR();                                    \
  }

__global__ __launch_bounds__(512, 2)
void sl_gemm_i8p(const char* __restrict__ A, const char* __restrict__ Bw,
                 const float* __restrict__ sx,
                 const float* __restrict__ scale_p, const float* __restrict__ bias,
                 float* __restrict__ Out)
{
    __shared__ char ldsbuf[131072];   // ring-4 x (A 16 KB + B 16 KB)
    char* ldsc = ldsbuf;

    const int t    = threadIdx.x;
    const int lane = t & 63;
    const int wave = t >> 6;        // 0..7
    const int wr   = wave >> 2;     // 0..1 : 128 output rows each
    const int wc   = wave & 3;      // 0..3 : 64  output cols each

    // ---- tile mapping (R13): XCD x = bid&7 owns tm in [4x,4x+4)
    //      (A rows [x*1024, x*1024+1024) = 4 MB i8, L2-resident slab)
    int bid = blockIdx.x;                       // 2048 blocks (32 tm x 64 tn)
    int tm = ((bid & 7) << 2) + ((bid >> 3) & 3);
    int tn = bid >> 5;
    const int m0 = tm << 8;
    const int n0 = tn << 8;

    // ---- staging geometry (verbatim R12): thread covers row
    //      (wave*16 + lane>>2) of a 128-row chunk, physical slot lane&3
    const int srow  = wave * 16 + (lane >> 2);            // 0..127
    const int sslot = lane & 3;
    const int sA    = sslot ^ ((srow >> 1) & 3);          // logical slot
    const char* pA0 = A  + (size_t)(m0 + srow) * KDIM + sA * 16;
    const char* pA1 = pA0 + (size_t)128 * KDIM;
    const char* pB0 = Bw + (size_t)(n0 + srow) * KDIM + sA * 16;
    const char* pB1 = pB0 + (size_t)128 * KDIM;
    const int ldsw = wave * 1024;                          // wave-uniform dest

    // ---- fragment read offsets (byte, buf-relative; verbatim R12)
    const int fr = lane & 15;
    const int fs = lane >> 4;                              // 0..3
    int aoff[8], boff[4];
    #pragma unroll
    for (int i = 0; i < 8; ++i) {
        int ra = wr * 128 + i * 16 + fr;
        aoff[i] = ra * 64 + ((fs ^ ((ra >> 1) & 3)) * 16);
    }
    #pragma unroll
    for (int j = 0; j < 4; ++j) {
        int rb = wc * 64 + j * 16 + fr;
        boff[j] = 16384 + rb * 64 + ((fs ^ ((rb >> 1) & 3)) * 16);
    }

    i32x4 acc[8][4];
    #pragma unroll
    for (int i = 0; i < 8; ++i)
        #pragma unroll
        for (int j = 0; j < 4; ++j)
            acc[i][j] = (i32x4){0, 0, 0, 0};

    i32x4 PA0[2], PA1[2], BF[4], BG[4];

    // ---- prologue: stage tiles 0,1,2 -> bufs 0,1,2
    #pragma unroll
    for (int kt = 0; kt < 3; ++kt) {
        const size_t ko = (size_t)kt * 64;
        char* b = ldsc + kt * 32768;
        gload_lds16(pA0 + ko, b + ldsw);
        gload_lds16(pA1 + ko, b + 8192  + ldsw);
        gload_lds16(pB0 + ko, b + 16384 + ldsw);
        gload_lds16(pB1 + ko, b + 24576 + ldsw);
    }
    asm volatile("s_waitcnt vmcnt(8)" ::: "memory");   // tile 0 landed
    BAR();
    SB0();

    // preload tile 0: B0-3 + A-frags 0,1 (ph0's lgkm(2) covers completion)
    BF[0] = *(const i32x4*)(ldsc + boff[0]);
    BF[1] = *(const i32x4*)(ldsc + boff[1]);
    BF[2] = *(const i32x4*)(ldsc + boff[2]);
    BF[3] = *(const i32x4*)(ldsc + boff[3]);
    PA0[0] = *(const i32x4*)(ldsc + aoff[0]);
    PA0[1] = *(const i32x4*)(ldsc + aoff[1]);

    // ring: iter even {R0,R1,R2,W0,W1}={0,1,2,3,0}; odd {2,3,0,1,2} (x32768)
    for (int tt = 0; tt < NKT; tt += 4) {
        ITER(0 * 32768, 1 * 32768, 2 * 32768, 3 * 32768, 0 * 32768, tt);
        ITER(2 * 32768, 3 * 32768, 0 * 32768, 1 * 32768, 2 * 32768, tt + 2);
    }

    // ---- epilogue: D col = lane&15, row = fs*4 + q; per-row dequant + bias
    const float scale = scale_p[0];
    #pragma unroll
    for (int i = 0; i < 8; ++i) {
        const int r0 = m0 + wr * 128 + i * 16 + fs * 4;
        float s4[4];
        #pragma unroll
        for (int q = 0; q < 4; ++q) s4[q] = sx[r0 + q] * scale;
        #pragma unroll
        for (int j = 0; j < 4; ++j) {
            const int c   = n0 + wc * 64 + j * 16 + fr;
            const float bj = bias[c];
            float* op = Out + (size_t)r0 * NDIM + c;
            #pragma unroll
            for (int q = 0; q < 4; ++q)
                op[(size_t)q * NDIM] = (float)acc[i][j][q] * s4[q] + bj;
        }
    }
}

// ---------------- fallback (fp32 direct, no workspace) ----------------

__global__ __launch_bounds__(256, 2)
void sl_gemm_fb(const float* __restrict__ X, const int* __restrict__ Wq,
                const float* __restrict__ scale_p, const float* __restrict__ bias,
                float* __restrict__ Out)
{
    __shared__ s16x8 As[128 * 4];
    __shared__ s16x8 Bs[128 * 4];

    const int t    = threadIdx.x;
    const int lane = t & 63;
    const int wave = t >> 6;
    const int wr   = wave >> 1;
    const int wc   = wave & 1;

    int bid = blockIdx.x;
    int swz = (bid & 7) * 1024 + (bid >> 3);
    int panel   = swz >> 10;
    int inpanel = swz & 1023;
    int tn = (panel << 4) + (inpanel >> 6);
    int tm = inpanel & 63;
    const int m0 = tm << 7;
    const int n0 = tn << 7;

    const int srow  = t >> 1;
    const int shalf = t & 1;
    const float* Xp = X  + (size_t)(m0 + srow) * KDIM + shalf * 16;
    const int*   Wp = Wq + (size_t)(n0 + srow) * KDIM + shalf * 16;

    f32x4 acc[4][4];
    #pragma unroll
    for (int i = 0; i < 4; ++i)
        #pragma unroll
        for (int j = 0; j < 4; ++j)
            acc[i][j] = (f32x4){0.f, 0.f, 0.f, 0.f};

    const int fr = lane & 15;
    const int fs = lane >> 4;

    f32x4 ar[4];
    i32x4 br[4];
    #pragma unroll
    for (int p = 0; p < 4; ++p) {
        ar[p] = *(const f32x4*)(Xp + p * 4);
        br[p] = *(const i32x4*)(Wp + p * 4);
    }

    const int wbase = srow * 4;
    const int wswz  = (srow >> 1) & 3;
    const int ws0   = (shalf * 2)     ^ wswz;
    const int ws1   = (shalf * 2 + 1) ^ wswz;

    for (int kt = 0; kt < KDIM / 32; ++kt) {
        __syncthreads();
        {
            s16x8 v0, v1;
            #pragma unroll
            for (int q = 0; q < 8; ++q) v0[q] = f2bf(ar[q >> 2][q & 3]);
            #pragma unroll
            for (int q = 0; q < 8; ++q) v1[q] = f2bf(ar[2 + (q >> 2)][q & 3]);
            As[wbase + ws0] = v0;
            As[wbase + ws1] = v1;
            s16x8 u0, u1;
            #pragma unroll
            for (int q = 0; q < 8; ++q) u0[q] = f2bf((float)br[q >> 2][q & 3]);
            #pragma unroll
            for (int q = 0; q < 8; ++q) u1[q] = f2bf((float)br[2 + (q >> 2)][q & 3]);
            Bs[wbase + ws0] = u0;
            Bs[wbase + ws1] = u1;
        }
        __syncthreads();

        if (kt + 1 < KDIM / 32) {
            const float* Xn = Xp + (size_t)(kt + 1) * 32;
            const int*   Wn = Wp + (size_t)(kt + 1) * 32;
            #pragma unroll
            for (int p = 0; p < 4; ++p) {
                ar[p] = *(const f32x4*)(Xn + p * 4);
                br[p] = *(const i32x4*)(Wn + p * 4);
            }
        }

        s16x8 af[4], bq[4];
        #pragma unroll
        for (int i = 0; i < 4; ++i) {
            int row = wr * 64 + i * 16 + fr;
            af[i] = As[row * 4 + (fs ^ ((row >> 1) & 3))];
        }
        #pragma unroll
        for (int j = 0; j < 4; ++j) {
            int col = wc * 64 + j * 16 + fr;
            bq[j] = Bs[col * 4 + (fs ^ ((col >> 1) & 3))];
        }
        #pragma unroll
        for (int i = 0; i < 4; ++i)
            #pragma unroll
            for (int j = 0; j < 4; ++j)
                acc[i][j] = __builtin_amdgcn_mfma_f32_16x16x32_bf16(
                    af[i], bq[j], acc[i][j], 0, 0, 0);
    }

    const float scale = scale_p[0];
    #pragma unroll
    for (int j = 0; j < 4; ++j) {
        const int c  = n0 + wc * 64 + j * 16 + fr;
        const float bj = bias[c];
        #pragma unroll
        for (int i = 0; i < 4; ++i) {
            const int r0 = m0 + wr * 64 + i * 16 + fs * 4;
            float* op = Out + (size_t)r0 * NDIM + c;
            #pragma unroll
            for (int q = 0; q < 4; ++q)
                op[(size_t)q * NDIM] = acc[i][j][q] * scale + bj;
        }
    }
}

extern "C" void kernel_launch(void* const* d_in, const int* in_sizes, int n_in,
                              void* d_out, int out_size, void* d_ws, size_t ws_size,
                              hipStream_t stream) {
    const float* X     = (const float*)d_in[0];
    const int*   Wq    = (const int*)d_in[1];   // int8 widened to int32 by harness
    const float* scale = (const float*)d_in[2];
    const float* bias  = (const float*)d_in[3];
    float*       Out   = (float*)d_out;

    const size_t xqB = (size_t)MDIM * KDIM;          // 33.5 MB
    const size_t wqB = (size_t)NDIM * KDIM;          // 67 MB
    const size_t sxB = (size_t)MDIM * sizeof(float); // 32 KB
    if (ws_size >= xqB + wqB + sxB) {
        char*  Xq  = (char*)d_ws;
        char*  Wq8 = (char*)d_ws + xqB;
        float* sx  = (float*)((char*)d_ws + xqB + wqB);
        hipLaunchKernelGGL(quant_x, dim3(MDIM), dim3(256), 0, stream, X, Xq, sx);
        hipLaunchKernelGGL(pack_w, dim3(2048), dim3(256), 0, stream,
                           Wq, Wq8, NDIM * KDIM / 16);
        hipLaunchKernelGGL(sl_gemm_i8p, dim3(2048), dim3(512), 0, stream,
                           Xq, Wq8, sx, scale, bias, Out);
    } else {
        hipLaunchKernelGGL(sl_gemm_fb, dim3(8192), dim3(256), 0, stream,
                           X, Wq, scale, bias, Out);
    }
}